// Round 22
// baseline (66.811 us; speedup 1.0000x reference)
//
#include <hip/hip_runtime.h>
#include <hip/hip_bf16.h>
#include <math.h>

#define NF 64
#define NC 16
#define MAIN_BLOCKS 250
#define MAIN_WAVES  5                  // 320 thr; 1250 waves == 1250 tiles EXACTLY
#define TPW 10                         // 16-sample subtiles per wave (160 samples)

typedef __bf16 bf16x8 __attribute__((ext_vector_type(8)));
typedef float f32x4 __attribute__((ext_vector_type(4)));
typedef unsigned int u32;

// async global->LDS, 16B/lane. LDS dest = wave-uniform base (HW adds lane*16).
__device__ __forceinline__ void stage16(const void* gsrc, void* ldst) {
    __builtin_amdgcn_global_load_lds(
        (const __attribute__((address_space(1))) u32*)gsrc,
        (__attribute__((address_space(3))) u32*)ldst,
        16, 0, 0);
}

// ---------------------------------------------------------------------------
// Kernel 1 v20 (unchanged): RANK-2 fused Cholesky + inverse, 32 rounds.
// ---------------------------------------------------------------------------
__global__ __launch_bounds__(256) void gmm_precompute(
    const float* __restrict__ cov,
    const float* __restrict__ means,
    const float* __restrict__ weights,
    __hip_bfloat16* __restrict__ g,
    float* __restrict__ t,
    float* __restrict__ Cc)
{
    const int w = threadIdx.x >> 6;   // wave 0..3: rows [16w,16w+16)
    const int c = threadIdx.x & 63;   // lane owns column c
    const int k = blockIdx.x;

    __shared__ __align__(16) float LT[NF][68];   // LT[j][r] = L[r][j]
    __shared__ float Xs[NF][65];                 // Xs[i][c] = G[i][c]
    __shared__ __align__(16) float wbA2[2][68];
    __shared__ __align__(16) float wbB2[2][68];
    __shared__ __align__(16) float gwA2[2][68];
    __shared__ __align__(16) float gwB2[2][68];

    float a_loc[16];
    {
        const float* src = cov + (long)k * NF * NF + (w * 16) * NF + c;
        #pragma unroll
        for (int r = 0; r < 16; ++r)
            a_loc[r] = src[r * NF];
    }

    float s_loc[16];
    #pragma unroll
    for (int r = 0; r < 16; ++r)
        s_loc[r] = (w * 16 + r == c) ? 1.0f : 0.0f;

    float logdiag = 0.0f;
    float gvA = 0.0f, gvB = 0.0f;     // owner wave's pending G rows

    #pragma unroll 1
    for (int q = 0; q < 4; ++q) {
        #pragma unroll
        for (int h = 0; h < 8; ++h) {          // round r = q*8+h; steps j, j+1
            const int j = q * 16 + 2 * h;
            float* wbA = wbA2[h & 1];
            float* wbB = wbB2[h & 1];
            float* gwA = gwA2[h & 1];
            float* gwB = gwB2[h & 1];

            if (w == q) {                       // publish A rows j, j+1
                wbA[c] = a_loc[2 * h];
                wbB[c] = a_loc[2 * h + 1];
            }
            if (j > 0) {                        // publish G rows j-2, j-1
                const int pw = (h == 0) ? (q - 1) : q;
                if (w == pw) {
                    gwA[c] = gvA;  Xs[j - 2][c] = gvA;
                    gwB[c] = gvB;  Xs[j - 1][c] = gvB;
                }
            }
            __syncthreads();

            // ---- Cholesky steps j, j+1 ----
            float ajc = wbA[c];
            float bjc = wbB[c];
            float d0  = wbA[j];
            float a1j = wbA[j + 1];
            float b1j = wbB[j + 1];
            float rd0 = __builtin_amdgcn_rcpf(d0);
            float k0  = a1j * rd0;
            float d1  = fmaf(-a1j, k0, b1j);
            float rd1 = __builtin_amdgcn_rcpf(d1);
            float rsq0 = __builtin_amdgcn_rcpf(sqrtf(d0));
            float rsq1 = __builtin_amdgcn_rcpf(sqrtf(d1));
            logdiag += 0.5f * (__logf(d0) + __logf(d1));
            float w1c = fmaf(-ajc, k0, bjc);
            LT[j][c]     = ajc * rsq0;
            LT[j + 1][c] = w1c * rsq1;
            float beta0 = ajc * rd0;
            float beta1 = w1c * rd1;
            {
                const float4* wvA = (const float4*)(wbA + w * 16);
                const float4* wvB = (const float4*)(wbB + w * 16);
                #pragma unroll
                for (int rr = 0; rr < 16; rr += 4) {
                    float4 vA = wvA[rr >> 2];
                    float4 vB = wvB[rr >> 2];
                    float t0 = fmaf(-vA.x, k0, vB.x);
                    float t1 = fmaf(-vA.y, k0, vB.y);
                    float t2 = fmaf(-vA.z, k0, vB.z);
                    float t3 = fmaf(-vA.w, k0, vB.w);
                    a_loc[rr]     = fmaf(-t0, beta1, fmaf(-vA.x, beta0, a_loc[rr]));
                    a_loc[rr + 1] = fmaf(-t1, beta1, fmaf(-vA.y, beta0, a_loc[rr + 1]));
                    a_loc[rr + 2] = fmaf(-t2, beta1, fmaf(-vA.z, beta0, a_loc[rr + 2]));
                    a_loc[rr + 3] = fmaf(-t3, beta1, fmaf(-vA.w, beta0, a_loc[rr + 3]));
                }
            }

            // ---- substitution steps j-2, j-1 ----
            if (j > 0) {
                float gA = gwA[c];
                float gB = gwB[c];
                const float4* lvA = (const float4*)(&LT[j - 2][w * 16]);
                const float4* lvB = (const float4*)(&LT[j - 1][w * 16]);
                #pragma unroll
                for (int rr = 0; rr < 16; rr += 4) {
                    float4 vA = lvA[rr >> 2];
                    float4 vB = lvB[rr >> 2];
                    s_loc[rr]     = fmaf(-vB.x, gB, fmaf(-vA.x, gA, s_loc[rr]));
                    s_loc[rr + 1] = fmaf(-vB.y, gB, fmaf(-vA.y, gA, s_loc[rr + 1]));
                    s_loc[rr + 2] = fmaf(-vB.z, gB, fmaf(-vA.z, gA, s_loc[rr + 2]));
                    s_loc[rr + 3] = fmaf(-vB.w, gB, fmaf(-vA.w, gA, s_loc[rr + 3]));
                }
            }

            // ---- end of round: owner computes G rows j, j+1 ----
            if (w == q) {
                float l10 = a1j * rsq0;
                gvA = s_loc[2 * h] * rsq0;
                gvB = fmaf(-l10, gvA, s_loc[2 * h + 1]) * rsq1;
            }
        }
    }

    if (w == 3) { Xs[62][c] = gvA; Xs[63][c] = gvB; }
    __syncthreads();

    // g row c: chunks jb=2w,2w+1, XOR-swizzled (jb ^ (row&7))
    {
        __hip_bfloat16* grow = g + ((long)(k * NF + c)) * NF;
        #pragma unroll
        for (int h = 0; h < 2; ++h) {
            int jb = w * 2 + h;
            bf16x8 v;
            #pragma unroll
            for (int u = 0; u < 8; ++u)
                v[u] = (__bf16)Xs[c][jb * 8 + u];
            *(bf16x8*)(grow + ((jb ^ (c & 7)) * 8)) = v;
        }
    }

    if (w == 0) {
        const float* mu = means + k * NF;
        float a0 = 0.0f, a1 = 0.0f;
        #pragma unroll
        for (int j = 0; j < NF; j += 2) {
            a0 = fmaf(Xs[c][j],     mu[j],     a0);
            a1 = fmaf(Xs[c][j + 1], mu[j + 1], a1);
        }
        t[k * NF + c] = a0 + a1;
        if (c == 0)
            Cc[k] = __logf(weights[k]) - 0.5f * (float)NF * 1.8378770664093453f - logdiag;
    }
}

// ---------------------------------------------------------------------------
// Kernel 2 v22: TPW=10, 5 waves/block, 250 blocks: 1250 waves == 1250 tiles
// EXACTLY. The 14 G/nt ds_reads per comp (TPW-independent) amortize over
// 160 samples: per-CU DS-G halves vs v21 (11.2 -> 5.6 us); per-CU
// MFMA/VALU/shfl totals unchanged. Regime is DS-throughput-dominant
// (waves/CU 13->10 improved perf), so sum-of-pipes drops ~5 us.
// Swizzle/tri-skip/stagger/defer-max unchanged.
// ---------------------------------------------------------------------------
__global__ __launch_bounds__(320) void gmm_main(
    const float* __restrict__ data,
    const char* __restrict__ gsw,         // swizzled bf16 G, [NC][8192 B]
    const float* __restrict__ t,
    const float* __restrict__ Cc,
    float* __restrict__ partials,
    int nTiles, int N, int totalWaves)
{
    __shared__ __align__(16) char gbuf[NC * 8192];   // 128 KiB
    __shared__ __align__(16) float nt_lds[NC * NF];  // negated t
    __shared__ float cc_lds[NC];

    const int tidx = threadIdx.x;
    const int w    = tidx >> 6;
    const int lane = tidx & 63;
    const int l15  = lane & 15;
    const int lg   = lane >> 4;

    // stage G: wave w covers comps {w, w+5, w+10, w+15} (<16)
    for (int i = w; i < NC; i += MAIN_WAVES) {
        const char* src = gsw + (size_t)i * 8192;
        char* dst = gbuf + (size_t)i * 8192;
        #pragma unroll
        for (int u = 0; u < 8; ++u)
            stage16(src + u * 1024 + lane * 16, dst + u * 1024);
    }

    for (int i = tidx; i < NC * NF; i += 64 * MAIN_WAVES) nt_lds[i] = -t[i];
    if (tidx < NC) cc_lds[tidx] = Cc[tidx];

    const int gid = blockIdx.x * MAIN_WAVES + w;

    // swizzled LDS byte offsets (static per lane)
    int offA[4], offB[4];
    #pragma unroll
    for (int rc = 0; rc < 4; ++rc) {
        int row = rc * 16 + l15;
        offA[rc] = row * 128 + ((lg       ^ (l15 & 7)) * 16);
        offB[rc] = row * 128 + (((lg + 4) ^ (l15 & 7)) * 16);
    }

    // first tile's x fragments (overlaps the staging flight)
    bf16x8 xf[TPW][2];
    if (gid < nTiles) {
        const long base = (long)gid * (TPW * 16);
        #pragma unroll
        for (int st = 0; st < TPW; ++st) {
            long row = base + st * 16 + l15;
            if (row > (long)N - 1) row = (long)N - 1;
            const float* xp = data + row * NF + lg * 8;
            float4 a0 = *(const float4*)(xp);
            float4 a1 = *(const float4*)(xp + 4);
            float4 b0 = *(const float4*)(xp + 32);
            float4 b1 = *(const float4*)(xp + 36);
            bf16x8 f0, f1;
            f0[0] = (__bf16)a0.x; f0[1] = (__bf16)a0.y;
            f0[2] = (__bf16)a0.z; f0[3] = (__bf16)a0.w;
            f0[4] = (__bf16)a1.x; f0[5] = (__bf16)a1.y;
            f0[6] = (__bf16)a1.z; f0[7] = (__bf16)a1.w;
            f1[0] = (__bf16)b0.x; f1[1] = (__bf16)b0.y;
            f1[2] = (__bf16)b0.z; f1[3] = (__bf16)b0.w;
            f1[4] = (__bf16)b1.x; f1[5] = (__bf16)b1.y;
            f1[6] = (__bf16)b1.z; f1[7] = (__bf16)b1.w;
            xf[st][0] = f0;
            xf[st][1] = f1;
        }
    }

    __syncthreads();   // G + t staged; only barrier in the kernel

    float wavePartial = 0.0f;

    #pragma unroll 1
    for (int tile = gid; tile < nTiles; tile += totalWaves) {
        const long base = (long)tile * (TPW * 16);
        if (tile != gid) {     // unreachable at N=200000 (exact balance)
            #pragma unroll
            for (int st = 0; st < TPW; ++st) {
                long row = base + st * 16 + l15;
                if (row > (long)N - 1) row = (long)N - 1;
                const float* xp = data + row * NF + lg * 8;
                float4 a0 = *(const float4*)(xp);
                float4 a1 = *(const float4*)(xp + 4);
                float4 b0 = *(const float4*)(xp + 32);
                float4 b1 = *(const float4*)(xp + 36);
                bf16x8 f0, f1;
                f0[0] = (__bf16)a0.x; f0[1] = (__bf16)a0.y;
                f0[2] = (__bf16)a0.z; f0[3] = (__bf16)a0.w;
                f0[4] = (__bf16)a1.x; f0[5] = (__bf16)a1.y;
                f0[6] = (__bf16)a1.z; f0[7] = (__bf16)a1.w;
                f1[0] = (__bf16)b0.x; f1[1] = (__bf16)b0.y;
                f1[2] = (__bf16)b0.z; f1[3] = (__bf16)b0.w;
                f1[4] = (__bf16)b1.x; f1[5] = (__bf16)b1.y;
                f1[6] = (__bf16)b1.z; f1[7] = (__bf16)b1.w;
                xf[st][0] = f0;
                xf[st][1] = f1;
            }
        }

        float m[TPW], s[TPW];
        #pragma unroll
        for (int st = 0; st < TPW; ++st) { m[st] = -INFINITY; s[st] = 0.0f; }

        #pragma unroll 2
        for (int ii = 0; ii < NC; ++ii) {
            const int kk = (ii + w) & (NC - 1);      // per-wave stagger
            float mah[TPW];
            #pragma unroll
            for (int st = 0; st < TPW; ++st) mah[st] = 0.0f;

            const char* gk = gbuf + kk * 8192;
            const float* ntk = &nt_lds[kk * NF];

            // rc 0,1: rows 0..31 of lower-tri G -> cols 32..63 are ZERO
            #pragma unroll
            for (int rc = 0; rc < 2; ++rc) {
                bf16x8 ga = *(const bf16x8*)(gk + offA[rc]);
                f32x4 ntv = *(const f32x4*)(ntk + rc * 16 + lg * 4);
                #pragma unroll
                for (int st = 0; st < TPW; ++st) {
                    f32x4 acc = ntv;
                    acc = __builtin_amdgcn_mfma_f32_16x16x32_bf16(ga, xf[st][0], acc, 0, 0, 0);
                    mah[st] = fmaf(acc[0], acc[0], mah[st]);
                    mah[st] = fmaf(acc[1], acc[1], mah[st]);
                    mah[st] = fmaf(acc[2], acc[2], mah[st]);
                    mah[st] = fmaf(acc[3], acc[3], mah[st]);
                }
            }
            // rc 2,3: full rows
            #pragma unroll
            for (int rc = 2; rc < 4; ++rc) {
                bf16x8 ga = *(const bf16x8*)(gk + offA[rc]);
                bf16x8 gb = *(const bf16x8*)(gk + offB[rc]);
                f32x4 ntv = *(const f32x4*)(ntk + rc * 16 + lg * 4);
                #pragma unroll
                for (int st = 0; st < TPW; ++st) {
                    f32x4 acc = ntv;
                    acc = __builtin_amdgcn_mfma_f32_16x16x32_bf16(ga, xf[st][0], acc, 0, 0, 0);
                    acc = __builtin_amdgcn_mfma_f32_16x16x32_bf16(gb, xf[st][1], acc, 0, 0, 0);
                    mah[st] = fmaf(acc[0], acc[0], mah[st]);
                    mah[st] = fmaf(acc[1], acc[1], mah[st]);
                    mah[st] = fmaf(acc[2], acc[2], mah[st]);
                    mah[st] = fmaf(acc[3], acc[3], mah[st]);
                }
            }

            // defer-max logsumexp
            float Ck = cc_lds[kk];
            float wlp[TPW];
            float dmax = -INFINITY;
            #pragma unroll
            for (int st = 0; st < TPW; ++st) {
                float v = mah[st];
                v += __shfl_xor(v, 16);
                v += __shfl_xor(v, 32);          // all lanes hold full maha
                wlp[st] = fmaf(-0.5f, v, Ck);
                dmax = fmaxf(dmax, wlp[st] - m[st]);
            }
            if (__any(dmax > 60.0f)) {           // rare after first comp
                #pragma unroll
                for (int st = 0; st < TPW; ++st) {
                    float mn = fmaxf(m[st], wlp[st]);
                    s[st] = s[st] * __expf(m[st] - mn) + __expf(wlp[st] - mn);
                    m[st] = mn;
                }
            } else {                             // common: 1 exp + 1 add
                #pragma unroll
                for (int st = 0; st < TPW; ++st)
                    s[st] += __expf(wlp[st] - m[st]);
            }
        }

        if (lg == 0) {
            #pragma unroll
            for (int st = 0; st < TPW; ++st) {
                long sid = base + st * 16 + l15;
                if (sid < (long)N)
                    wavePartial += m[st] + __logf(s[st]);
            }
        }
    }

    #pragma unroll
    for (int off = 1; off < 64; off <<= 1)
        wavePartial += __shfl_xor(wavePartial, off);
    if (lane == 0)
        partials[gid] = wavePartial;
}

// ---------------------------------------------------------------------------
// Kernel 3: deterministic final reduction over per-wave partials.
// ---------------------------------------------------------------------------
__global__ __launch_bounds__(256) void gmm_reduce(
    const float* __restrict__ partials, int n, float* __restrict__ out)
{
    float s = 0.0f;
    for (int i = threadIdx.x; i < n; i += 256)
        s += partials[i];
    #pragma unroll
    for (int off = 1; off < 64; off <<= 1)
        s += __shfl_xor(s, off);
    __shared__ float sm[4];
    const int wave = threadIdx.x >> 6;
    const int lane = threadIdx.x & 63;
    if (lane == 0) sm[wave] = s;
    __syncthreads();
    if (threadIdx.x == 0)
        out[0] = (sm[0] + sm[1]) + (sm[2] + sm[3]);
}

// ---------------------------------------------------------------------------
extern "C" void kernel_launch(void* const* d_in, const int* in_sizes, int n_in,
                              void* d_out, int out_size, void* d_ws, size_t ws_size,
                              hipStream_t stream)
{
    const float* data    = (const float*)d_in[0];
    const float* weights = (const float*)d_in[1];
    const float* means   = (const float*)d_in[2];
    const float* cov     = (const float*)d_in[3];

    const int N = in_sizes[0] / NF;

    char* ws = (char*)d_ws;
    __hip_bfloat16* g = (__hip_bfloat16*)ws;                    // 131072 B (swizzled)
    float* t          = (float*)(ws + 131072);                  // 4096 B
    float* Cc         = (float*)(ws + 131072 + 4096);           // 64 B
    float* partials   = (float*)(ws + 131072 + 4096 + 64);      // totalWaves * 4 B

    const int nTiles     = (N + TPW * 16 - 1) / (TPW * 16);
    const int totalWaves = MAIN_BLOCKS * MAIN_WAVES;

    gmm_precompute<<<NC, 256, 0, stream>>>(cov, means, weights, g, t, Cc);
    gmm_main<<<MAIN_BLOCKS, 64 * MAIN_WAVES, 0, stream>>>(
        data, (const char*)g, t, Cc, partials, nTiles, N, totalWaves);
    gmm_reduce<<<1, 256, 0, stream>>>(partials, totalWaves, (float*)d_out);
}

// Round 23
// 60.188 us; speedup vs baseline: 1.1100x; 1.1100x over previous
//
#include <hip/hip_runtime.h>
#include <hip/hip_bf16.h>
#include <math.h>

#define NF 64
#define NC 16
#define MAIN_BLOCKS 250
#define MAIN_WAVES  10                 // 640 thr; 2500 waves == 2500 tiles EXACTLY
#define TPW 5                          // 16-sample subtiles per wave (80 samples)

typedef __bf16 bf16x8 __attribute__((ext_vector_type(8)));
typedef float f32x4 __attribute__((ext_vector_type(4)));
typedef unsigned int u32;

// async global->LDS, 16B/lane. LDS dest = wave-uniform base (HW adds lane*16).
__device__ __forceinline__ void stage16(const void* gsrc, void* ldst) {
    __builtin_amdgcn_global_load_lds(
        (const __attribute__((address_space(1))) u32*)gsrc,
        (__attribute__((address_space(3))) u32*)ldst,
        16, 0, 0);
}

// ---------------------------------------------------------------------------
// Kernel 1 v20 (unchanged): RANK-2 fused Cholesky + inverse, 32 rounds.
// ---------------------------------------------------------------------------
__global__ __launch_bounds__(256) void gmm_precompute(
    const float* __restrict__ cov,
    const float* __restrict__ means,
    const float* __restrict__ weights,
    __hip_bfloat16* __restrict__ g,
    float* __restrict__ t,
    float* __restrict__ Cc)
{
    const int w = threadIdx.x >> 6;   // wave 0..3: rows [16w,16w+16)
    const int c = threadIdx.x & 63;   // lane owns column c
    const int k = blockIdx.x;

    __shared__ __align__(16) float LT[NF][68];   // LT[j][r] = L[r][j]
    __shared__ float Xs[NF][65];                 // Xs[i][c] = G[i][c]
    __shared__ __align__(16) float wbA2[2][68];
    __shared__ __align__(16) float wbB2[2][68];
    __shared__ __align__(16) float gwA2[2][68];
    __shared__ __align__(16) float gwB2[2][68];

    float a_loc[16];
    {
        const float* src = cov + (long)k * NF * NF + (w * 16) * NF + c;
        #pragma unroll
        for (int r = 0; r < 16; ++r)
            a_loc[r] = src[r * NF];
    }

    float s_loc[16];
    #pragma unroll
    for (int r = 0; r < 16; ++r)
        s_loc[r] = (w * 16 + r == c) ? 1.0f : 0.0f;

    float logdiag = 0.0f;
    float gvA = 0.0f, gvB = 0.0f;     // owner wave's pending G rows

    #pragma unroll 1
    for (int q = 0; q < 4; ++q) {
        #pragma unroll
        for (int h = 0; h < 8; ++h) {          // round r = q*8+h; steps j, j+1
            const int j = q * 16 + 2 * h;
            float* wbA = wbA2[h & 1];
            float* wbB = wbB2[h & 1];
            float* gwA = gwA2[h & 1];
            float* gwB = gwB2[h & 1];

            if (w == q) {                       // publish A rows j, j+1
                wbA[c] = a_loc[2 * h];
                wbB[c] = a_loc[2 * h + 1];
            }
            if (j > 0) {                        // publish G rows j-2, j-1
                const int pw = (h == 0) ? (q - 1) : q;
                if (w == pw) {
                    gwA[c] = gvA;  Xs[j - 2][c] = gvA;
                    gwB[c] = gvB;  Xs[j - 1][c] = gvB;
                }
            }
            __syncthreads();

            // ---- Cholesky steps j, j+1 ----
            float ajc = wbA[c];
            float bjc = wbB[c];
            float d0  = wbA[j];
            float a1j = wbA[j + 1];
            float b1j = wbB[j + 1];
            float rd0 = __builtin_amdgcn_rcpf(d0);
            float k0  = a1j * rd0;
            float d1  = fmaf(-a1j, k0, b1j);
            float rd1 = __builtin_amdgcn_rcpf(d1);
            float rsq0 = __builtin_amdgcn_rcpf(sqrtf(d0));
            float rsq1 = __builtin_amdgcn_rcpf(sqrtf(d1));
            logdiag += 0.5f * (__logf(d0) + __logf(d1));
            float w1c = fmaf(-ajc, k0, bjc);
            LT[j][c]     = ajc * rsq0;
            LT[j + 1][c] = w1c * rsq1;
            float beta0 = ajc * rd0;
            float beta1 = w1c * rd1;
            {
                const float4* wvA = (const float4*)(wbA + w * 16);
                const float4* wvB = (const float4*)(wbB + w * 16);
                #pragma unroll
                for (int rr = 0; rr < 16; rr += 4) {
                    float4 vA = wvA[rr >> 2];
                    float4 vB = wvB[rr >> 2];
                    float t0 = fmaf(-vA.x, k0, vB.x);
                    float t1 = fmaf(-vA.y, k0, vB.y);
                    float t2 = fmaf(-vA.z, k0, vB.z);
                    float t3 = fmaf(-vA.w, k0, vB.w);
                    a_loc[rr]     = fmaf(-t0, beta1, fmaf(-vA.x, beta0, a_loc[rr]));
                    a_loc[rr + 1] = fmaf(-t1, beta1, fmaf(-vA.y, beta0, a_loc[rr + 1]));
                    a_loc[rr + 2] = fmaf(-t2, beta1, fmaf(-vA.z, beta0, a_loc[rr + 2]));
                    a_loc[rr + 3] = fmaf(-t3, beta1, fmaf(-vA.w, beta0, a_loc[rr + 3]));
                }
            }

            // ---- substitution steps j-2, j-1 ----
            if (j > 0) {
                float gA = gwA[c];
                float gB = gwB[c];
                const float4* lvA = (const float4*)(&LT[j - 2][w * 16]);
                const float4* lvB = (const float4*)(&LT[j - 1][w * 16]);
                #pragma unroll
                for (int rr = 0; rr < 16; rr += 4) {
                    float4 vA = lvA[rr >> 2];
                    float4 vB = lvB[rr >> 2];
                    s_loc[rr]     = fmaf(-vB.x, gB, fmaf(-vA.x, gA, s_loc[rr]));
                    s_loc[rr + 1] = fmaf(-vB.y, gB, fmaf(-vA.y, gA, s_loc[rr + 1]));
                    s_loc[rr + 2] = fmaf(-vB.z, gB, fmaf(-vA.z, gA, s_loc[rr + 2]));
                    s_loc[rr + 3] = fmaf(-vB.w, gB, fmaf(-vA.w, gA, s_loc[rr + 3]));
                }
            }

            // ---- end of round: owner computes G rows j, j+1 ----
            if (w == q) {
                float l10 = a1j * rsq0;
                gvA = s_loc[2 * h] * rsq0;
                gvB = fmaf(-l10, gvA, s_loc[2 * h + 1]) * rsq1;
            }
        }
    }

    if (w == 3) { Xs[62][c] = gvA; Xs[63][c] = gvB; }
    __syncthreads();

    // g row c: chunks jb=2w,2w+1, XOR-swizzled (jb ^ (row&7))
    {
        __hip_bfloat16* grow = g + ((long)(k * NF + c)) * NF;
        #pragma unroll
        for (int h = 0; h < 2; ++h) {
            int jb = w * 2 + h;
            bf16x8 v;
            #pragma unroll
            for (int u = 0; u < 8; ++u)
                v[u] = (__bf16)Xs[c][jb * 8 + u];
            *(bf16x8*)(grow + ((jb ^ (c & 7)) * 8)) = v;
        }
    }

    if (w == 0) {
        const float* mu = means + k * NF;
        float a0 = 0.0f, a1 = 0.0f;
        #pragma unroll
        for (int j = 0; j < NF; j += 2) {
            a0 = fmaf(Xs[c][j],     mu[j],     a0);
            a1 = fmaf(Xs[c][j + 1], mu[j + 1], a1);
        }
        t[k * NF + c] = a0 + a1;
        if (c == 0)
            Cc[k] = __logf(weights[k]) - 0.5f * (float)NF * 1.8378770664093453f - logdiag;
    }
}

// ---------------------------------------------------------------------------
// Kernel 2 v21 (best measured): TPW=5, 10 waves/block, 250 blocks —
// 2500 waves == 2500 tiles exactly; occupancy sweep (13/10/5 waves ->
// 40/38/45 us) shows this is the DS-amortization vs latency-hiding optimum.
// Swizzle/tri-skip/stagger/defer-max unchanged.
// ---------------------------------------------------------------------------
__global__ __launch_bounds__(640) void gmm_main(
    const float* __restrict__ data,
    const char* __restrict__ gsw,         // swizzled bf16 G, [NC][8192 B]
    const float* __restrict__ t,
    const float* __restrict__ Cc,
    float* __restrict__ partials,
    int nTiles, int N, int totalWaves)
{
    __shared__ __align__(16) char gbuf[NC * 8192];   // 128 KiB
    __shared__ __align__(16) float nt_lds[NC * NF];  // negated t
    __shared__ float cc_lds[NC];

    const int tidx = threadIdx.x;
    const int w    = tidx >> 6;
    const int lane = tidx & 63;
    const int l15  = lane & 15;
    const int lg   = lane >> 4;

    // stage G: wave w covers comps {w, w+10} (<16)
    for (int i = w; i < NC; i += MAIN_WAVES) {
        const char* src = gsw + (size_t)i * 8192;
        char* dst = gbuf + (size_t)i * 8192;
        #pragma unroll
        for (int u = 0; u < 8; ++u)
            stage16(src + u * 1024 + lane * 16, dst + u * 1024);
    }

    for (int i = tidx; i < NC * NF; i += 64 * MAIN_WAVES) nt_lds[i] = -t[i];
    if (tidx < NC) cc_lds[tidx] = Cc[tidx];

    const int gid = blockIdx.x * MAIN_WAVES + w;

    // swizzled LDS byte offsets (static per lane)
    int offA[4], offB[4];
    #pragma unroll
    for (int rc = 0; rc < 4; ++rc) {
        int row = rc * 16 + l15;
        offA[rc] = row * 128 + ((lg       ^ (l15 & 7)) * 16);
        offB[rc] = row * 128 + (((lg + 4) ^ (l15 & 7)) * 16);
    }

    // first tile's x fragments (overlaps the staging flight)
    bf16x8 xf[TPW][2];
    if (gid < nTiles) {
        const long base = (long)gid * (TPW * 16);
        #pragma unroll
        for (int st = 0; st < TPW; ++st) {
            long row = base + st * 16 + l15;
            if (row > (long)N - 1) row = (long)N - 1;
            const float* xp = data + row * NF + lg * 8;
            float4 a0 = *(const float4*)(xp);
            float4 a1 = *(const float4*)(xp + 4);
            float4 b0 = *(const float4*)(xp + 32);
            float4 b1 = *(const float4*)(xp + 36);
            bf16x8 f0, f1;
            f0[0] = (__bf16)a0.x; f0[1] = (__bf16)a0.y;
            f0[2] = (__bf16)a0.z; f0[3] = (__bf16)a0.w;
            f0[4] = (__bf16)a1.x; f0[5] = (__bf16)a1.y;
            f0[6] = (__bf16)a1.z; f0[7] = (__bf16)a1.w;
            f1[0] = (__bf16)b0.x; f1[1] = (__bf16)b0.y;
            f1[2] = (__bf16)b0.z; f1[3] = (__bf16)b0.w;
            f1[4] = (__bf16)b1.x; f1[5] = (__bf16)b1.y;
            f1[6] = (__bf16)b1.z; f1[7] = (__bf16)b1.w;
            xf[st][0] = f0;
            xf[st][1] = f1;
        }
    }

    __syncthreads();   // G + t staged; only barrier in the kernel

    float wavePartial = 0.0f;

    #pragma unroll 1
    for (int tile = gid; tile < nTiles; tile += totalWaves) {
        const long base = (long)tile * (TPW * 16);
        if (tile != gid) {     // unreachable at N=200000 (exact balance)
            #pragma unroll
            for (int st = 0; st < TPW; ++st) {
                long row = base + st * 16 + l15;
                if (row > (long)N - 1) row = (long)N - 1;
                const float* xp = data + row * NF + lg * 8;
                float4 a0 = *(const float4*)(xp);
                float4 a1 = *(const float4*)(xp + 4);
                float4 b0 = *(const float4*)(xp + 32);
                float4 b1 = *(const float4*)(xp + 36);
                bf16x8 f0, f1;
                f0[0] = (__bf16)a0.x; f0[1] = (__bf16)a0.y;
                f0[2] = (__bf16)a0.z; f0[3] = (__bf16)a0.w;
                f0[4] = (__bf16)a1.x; f0[5] = (__bf16)a1.y;
                f0[6] = (__bf16)a1.z; f0[7] = (__bf16)a1.w;
                f1[0] = (__bf16)b0.x; f1[1] = (__bf16)b0.y;
                f1[2] = (__bf16)b0.z; f1[3] = (__bf16)b0.w;
                f1[4] = (__bf16)b1.x; f1[5] = (__bf16)b1.y;
                f1[6] = (__bf16)b1.z; f1[7] = (__bf16)b1.w;
                xf[st][0] = f0;
                xf[st][1] = f1;
            }
        }

        float m[TPW], s[TPW];
        #pragma unroll
        for (int st = 0; st < TPW; ++st) { m[st] = -INFINITY; s[st] = 0.0f; }

        #pragma unroll 2
        for (int ii = 0; ii < NC; ++ii) {
            const int kk = (ii + w) & (NC - 1);      // per-wave stagger
            float mah[TPW];
            #pragma unroll
            for (int st = 0; st < TPW; ++st) mah[st] = 0.0f;

            const char* gk = gbuf + kk * 8192;
            const float* ntk = &nt_lds[kk * NF];

            // rc 0,1: rows 0..31 of lower-tri G -> cols 32..63 are ZERO
            #pragma unroll
            for (int rc = 0; rc < 2; ++rc) {
                bf16x8 ga = *(const bf16x8*)(gk + offA[rc]);
                f32x4 ntv = *(const f32x4*)(ntk + rc * 16 + lg * 4);
                #pragma unroll
                for (int st = 0; st < TPW; ++st) {
                    f32x4 acc = ntv;
                    acc = __builtin_amdgcn_mfma_f32_16x16x32_bf16(ga, xf[st][0], acc, 0, 0, 0);
                    mah[st] = fmaf(acc[0], acc[0], mah[st]);
                    mah[st] = fmaf(acc[1], acc[1], mah[st]);
                    mah[st] = fmaf(acc[2], acc[2], mah[st]);
                    mah[st] = fmaf(acc[3], acc[3], mah[st]);
                }
            }
            // rc 2,3: full rows
            #pragma unroll
            for (int rc = 2; rc < 4; ++rc) {
                bf16x8 ga = *(const bf16x8*)(gk + offA[rc]);
                bf16x8 gb = *(const bf16x8*)(gk + offB[rc]);
                f32x4 ntv = *(const f32x4*)(ntk + rc * 16 + lg * 4);
                #pragma unroll
                for (int st = 0; st < TPW; ++st) {
                    f32x4 acc = ntv;
                    acc = __builtin_amdgcn_mfma_f32_16x16x32_bf16(ga, xf[st][0], acc, 0, 0, 0);
                    acc = __builtin_amdgcn_mfma_f32_16x16x32_bf16(gb, xf[st][1], acc, 0, 0, 0);
                    mah[st] = fmaf(acc[0], acc[0], mah[st]);
                    mah[st] = fmaf(acc[1], acc[1], mah[st]);
                    mah[st] = fmaf(acc[2], acc[2], mah[st]);
                    mah[st] = fmaf(acc[3], acc[3], mah[st]);
                }
            }

            // defer-max logsumexp
            float Ck = cc_lds[kk];
            float wlp[TPW];
            float dmax = -INFINITY;
            #pragma unroll
            for (int st = 0; st < TPW; ++st) {
                float v = mah[st];
                v += __shfl_xor(v, 16);
                v += __shfl_xor(v, 32);          // all lanes hold full maha
                wlp[st] = fmaf(-0.5f, v, Ck);
                dmax = fmaxf(dmax, wlp[st] - m[st]);
            }
            if (__any(dmax > 60.0f)) {           // rare after first comp
                #pragma unroll
                for (int st = 0; st < TPW; ++st) {
                    float mn = fmaxf(m[st], wlp[st]);
                    s[st] = s[st] * __expf(m[st] - mn) + __expf(wlp[st] - mn);
                    m[st] = mn;
                }
            } else {                             // common: 1 exp + 1 add
                #pragma unroll
                for (int st = 0; st < TPW; ++st)
                    s[st] += __expf(wlp[st] - m[st]);
            }
        }

        if (lg == 0) {
            #pragma unroll
            for (int st = 0; st < TPW; ++st) {
                long sid = base + st * 16 + l15;
                if (sid < (long)N)
                    wavePartial += m[st] + __logf(s[st]);
            }
        }
    }

    #pragma unroll
    for (int off = 1; off < 64; off <<= 1)
        wavePartial += __shfl_xor(wavePartial, off);
    if (lane == 0)
        partials[gid] = wavePartial;
}

// ---------------------------------------------------------------------------
// Kernel 3: deterministic final reduction over per-wave partials.
// ---------------------------------------------------------------------------
__global__ __launch_bounds__(256) void gmm_reduce(
    const float* __restrict__ partials, int n, float* __restrict__ out)
{
    float s = 0.0f;
    for (int i = threadIdx.x; i < n; i += 256)
        s += partials[i];
    #pragma unroll
    for (int off = 1; off < 64; off <<= 1)
        s += __shfl_xor(s, off);
    __shared__ float sm[4];
    const int wave = threadIdx.x >> 6;
    const int lane = threadIdx.x & 63;
    if (lane == 0) sm[wave] = s;
    __syncthreads();
    if (threadIdx.x == 0)
        out[0] = (sm[0] + sm[1]) + (sm[2] + sm[3]);
}

// ---------------------------------------------------------------------------
extern "C" void kernel_launch(void* const* d_in, const int* in_sizes, int n_in,
                              void* d_out, int out_size, void* d_ws, size_t ws_size,
                              hipStream_t stream)
{
    const float* data    = (const float*)d_in[0];
    const float* weights = (const float*)d_in[1];
    const float* means   = (const float*)d_in[2];
    const float* cov     = (const float*)d_in[3];

    const int N = in_sizes[0] / NF;

    char* ws = (char*)d_ws;
    __hip_bfloat16* g = (__hip_bfloat16*)ws;                    // 131072 B (swizzled)
    float* t          = (float*)(ws + 131072);                  // 4096 B
    float* Cc         = (float*)(ws + 131072 + 4096);           // 64 B
    float* partials   = (float*)(ws + 131072 + 4096 + 64);      // totalWaves * 4 B

    const int nTiles     = (N + TPW * 16 - 1) / (TPW * 16);
    const int totalWaves = MAIN_BLOCKS * MAIN_WAVES;

    gmm_precompute<<<NC, 256, 0, stream>>>(cov, means, weights, g, t, Cc);
    gmm_main<<<MAIN_BLOCKS, 64 * MAIN_WAVES, 0, stream>>>(
        data, (const char*)g, t, Cc, partials, nTiles, N, totalWaves);
    gmm_reduce<<<1, 256, 0, stream>>>(partials, totalWaves, (float*)d_out);
}